// Round 14
// baseline (346.751 us; speedup 1.0000x reference)
//
#include <hip/hip_runtime.h>

#define NN 100000
#define NE 600000
#define NG 64
#define FD 128
#define NB 98   // scan blocks of 1024: 98*1024 >= NN
#define EPAD 900000  // padded edge capacity: NE + 3*NN
#define NTILE16 6250   // 100000 / 16 row-tiles
#define GEMM_BLOCKS 512   // 2 blocks/CU (64 KB LDS each), 8 waves/block

typedef __attribute__((ext_vector_type(8))) short s8v;
typedef __attribute__((ext_vector_type(4))) float f4v;

__device__ inline float bflo(unsigned u) { return __uint_as_float(u << 16); }
__device__ inline float bfhi(unsigned u) { return __uint_as_float(u & 0xFFFF0000u); }
__device__ inline unsigned f2bfbits(float f) {  // round-to-nearest-even
  unsigned x = __float_as_uint(f);
  return (x + 0x7FFFu + ((x >> 16) & 1u)) >> 16;
}
__device__ inline unsigned pack2(float a, float b) { return f2bfbits(a) | (f2bfbits(b) << 16); }

// ---------------- weight cast: W f32 [K][N] -> WThi/WTlo bf16 [N][K], 3 weights in one ----------------
__global__ void k_castW3(const float* __restrict__ W1, const float* __restrict__ W2,
                         const float* __restrict__ W3, unsigned short* __restrict__ WTh,
                         unsigned short* __restrict__ WTl) {
  int e = blockIdx.x * 256 + threadIdx.x;   // grid covers 3*FD*FD
  int which = e / (FD * FD);
  int r = e - which * (FD * FD);
  if (which >= 3) return;
  const float* W = which == 0 ? W1 : (which == 1 ? W2 : W3);
  int k = r >> 7, n = r & 127;
  float v = W[r];
  unsigned hb = f2bfbits(v);
  float hf = __uint_as_float(hb << 16);
  unsigned lb = f2bfbits(v - hf);
  WTh[which * FD * FD + n * FD + k] = (unsigned short)hb;
  WTl[which * FD * FD + n * FD + k] = (unsigned short)lb;
}

// ---------------- degree / CSR build ----------------

__global__ void k_init(float* psum) {
  int i = blockIdx.x * 256 + threadIdx.x;
  if (i < NG * FD) psum[i] = 0.f;
}

__global__ void k_count(const int* __restrict__ col, int* __restrict__ counts) {
  int e = blockIdx.x * 256 + threadIdx.x;
  if (e < NE) atomicAdd(&counts[col[e]], 1);
}

__global__ void k_dinv(const int* __restrict__ counts, float* __restrict__ dinv) {
  int n = blockIdx.x * 256 + threadIdx.x;
  if (n < NN) dinv[n] = rsqrtf((float)counts[n] + 1.0f);
}

// 3-phase scan over PADDED counts: ceil(deg/4)*4 per node
__global__ void k_bsum(const int* __restrict__ counts, int* __restrict__ bsum) {
  __shared__ int wsm[16];
  int b = blockIdx.x, t = threadIdx.x;
  int i = b * 1024 + t;
  int x = (i < NN) ? ((counts[i] + 3) & ~3) : 0;
#pragma unroll
  for (int d = 32; d; d >>= 1) x += __shfl_down(x, d);
  if ((t & 63) == 0) wsm[t >> 6] = x;
  __syncthreads();
  if (t < 16) {
    int s = wsm[t];
#pragma unroll
    for (int d = 8; d; d >>= 1) s += __shfl_down(s, d);
    if (t == 0) bsum[b] = s;
  }
}

__global__ void k_bscan(const int* __restrict__ bsum, int* __restrict__ eb) {
  __shared__ int w0;
  int t = threadIdx.x;  // 128
  int x = (t < NB) ? bsum[t] : 0;
  int lane = t & 63;
  int inc = x;
#pragma unroll
  for (int d = 1; d < 64; d <<= 1) { int y = __shfl_up(inc, d); if (lane >= d) inc += y; }
  if (t == 63) w0 = inc;
  __syncthreads();
  int off = (t >= 64) ? w0 : 0;
  if (t < NB) eb[t] = off + inc - x;  // exclusive
}

__global__ void k_scan2(const int* __restrict__ counts, const int* __restrict__ eb,
                        int* __restrict__ indptr) {
  __shared__ int wsm[16];
  int b = blockIdx.x, t = threadIdx.x;
  int i = b * 1024 + t;
  int x = (i < NN) ? ((counts[i] + 3) & ~3) : 0;
  int lane = t & 63, wid = t >> 6;
  int inc = x;
#pragma unroll
  for (int d = 1; d < 64; d <<= 1) { int y = __shfl_up(inc, d); if (lane >= d) inc += y; }
  if (lane == 63) wsm[wid] = inc;
  __syncthreads();
  if (wid == 0) {
    int s = (lane < 16) ? wsm[lane] : 0;
#pragma unroll
    for (int d = 1; d < 16; d <<= 1) { int y = __shfl_up(s, d); if (lane >= d) s += y; }
    if (lane < 16) wsm[lane] = s;
  }
  __syncthreads();
  int woff = wid ? wsm[wid - 1] : 0;
  if (i < NN) indptr[i + 1] = eb[b] + woff + inc;
  if (i == 0) indptr[0] = 0;
}

// combined edge record: {src, nrm}; pad slots stay {0, 0.0f} from memset (exact no-ops)
__global__ void k_fill(const int* __restrict__ row, const int* __restrict__ col,
                       const int* __restrict__ indptr, int* __restrict__ cursor,
                       const float* __restrict__ dinv, uint2* __restrict__ edges) {
  int e = blockIdx.x * 256 + threadIdx.x;
  if (e >= NE) return;
  int c = col[e], r = row[e];
  int p = indptr[c] + atomicAdd(&cursor[c], 1);
  edges[p] = make_uint2((unsigned)r, __float_as_uint(dinv[r] * dinv[c]));
}

// batch is sorted: ranges by boundary detection
__global__ void k_ranges(const int* __restrict__ batch, int* __restrict__ starts,
                         int* __restrict__ ends) {
  int n = blockIdx.x * 256 + threadIdx.x;
  if (n >= NN) return;
  int g = batch[n];
  if (n == 0) {
    starts[g] = 0;
    for (int q = 0; q < g; ++q) { starts[q] = 0; ends[q] = 0; }
  } else {
    int gp = batch[n - 1];
    if (gp != g) {
      ends[gp] = n;
      starts[g] = n;
      for (int q = gp + 1; q < g; ++q) { starts[q] = n; ends[q] = n; }
    }
  }
  if (n == NN - 1) {
    ends[g] = NN;
    for (int q = g + 1; q < NG; ++q) { starts[q] = NN; ends[q] = NN; }
  }
}

// ---------------- MFMA GEMM: Hb[M,128] = A[M,128] @ (WThi+WTlo)^T ----------------
// 512-thread blocks, plain __launch_bounds__(512) — no min-wave cap (the cap
// caused R10-12's scratch-spill blowup; uncapped R13 wrote clean 25 MB).
// 2 blocks/CU (64 KB LDS) -> 16 waves/CU iff VGPR<=128; bh/bl in batches of 4
// to trim live regs. W staged once (XOR-swizzled), barrier-free persistent loop
// over 16-row tiles, swapped MFMA operands, one-tile-ahead A prefetch, uint2
// burst epilogue.
template <int F32A>
__global__ __launch_bounds__(512) void k_gemm(const void* __restrict__ Aab,
                                              const unsigned short* __restrict__ WThi,
                                              const unsigned short* __restrict__ WTlo,
                                              unsigned short* __restrict__ Hb) {
  __shared__ unsigned short wt[256 * 128];  // rows 0..127 = hi, 128..255 = lo
  int t = threadIdx.x, lane = t & 63, w = t >> 6;
  int r16 = lane & 15, kg = lane >> 4;

  {  // stage: thread t stages half a row (8 chunks of 8 us), swizzled ch = kap ^ (row&7)
    int rw = t >> 1, half = t & 1;
    const unsigned short* src = (rw < 128) ? (WThi + rw * FD) : (WTlo + (rw - 128) * FD);
#pragma unroll
    for (int j = 0; j < 8; ++j) {
      int kap = half * 8 + j;
      int ch = kap ^ (rw & 7);
      *(s8v*)&wt[rw * 128 + ch * 8] = *(const s8v*)(src + kap * 8);
    }
  }
  __syncthreads();

  const int stride = GEMM_BLOCKS * 8;
  int tile = blockIdx.x * 8 + w;   // 4096 waves over 6250 tiles

  float4 curF[8], nxtF[8];
  s8v curB[4], nxtB[4];

  if (tile < NTILE16) {  // load current tile's A (raw)
    int ar = tile * 16 + r16;
    if (F32A) {
      const float* ap = (const float*)Aab + (size_t)ar * FD + kg * 8;
#pragma unroll
      for (int c = 0; c < 4; ++c) {
        curF[c * 2] = *(const float4*)(ap + c * 32);
        curF[c * 2 + 1] = *(const float4*)(ap + c * 32 + 4);
      }
    } else {
      const unsigned short* ap = (const unsigned short*)Aab + (size_t)ar * FD + kg * 8;
#pragma unroll
      for (int c = 0; c < 4; ++c) curB[c] = *(const s8v*)(ap + c * 32);
    }
  }

  while (tile < NTILE16) {
    int next = tile + stride;
    int nld = (next < NTILE16) ? next : tile;  // dummy reload on last iter

    {  // issue next tile's A loads now — they complete under this tile's compute
      int ar = nld * 16 + r16;
      if (F32A) {
        const float* ap = (const float*)Aab + (size_t)ar * FD + kg * 8;
#pragma unroll
        for (int c = 0; c < 4; ++c) {
          nxtF[c * 2] = *(const float4*)(ap + c * 32);
          nxtF[c * 2 + 1] = *(const float4*)(ap + c * 32 + 4);
        }
      } else {
        const unsigned short* ap = (const unsigned short*)Aab + (size_t)ar * FD + kg * 8;
#pragma unroll
        for (int c = 0; c < 4; ++c) nxtB[c] = *(const s8v*)(ap + c * 32);
      }
    }

    // convert current raw A -> bf16 fragments
    s8v afr[4];
    if (F32A) {
#pragma unroll
      for (int c = 0; c < 4; ++c) {
        float4 p0 = curF[c * 2], p1 = curF[c * 2 + 1];
        s8v f;
        f[0] = (short)f2bfbits(p0.x); f[1] = (short)f2bfbits(p0.y);
        f[2] = (short)f2bfbits(p0.z); f[3] = (short)f2bfbits(p0.w);
        f[4] = (short)f2bfbits(p1.x); f[5] = (short)f2bfbits(p1.y);
        f[6] = (short)f2bfbits(p1.z); f[7] = (short)f2bfbits(p1.w);
        afr[c] = f;
      }
    } else {
#pragma unroll
      for (int c = 0; c < 4; ++c) afr[c] = curB[c];
    }

    f4v acc[8];
#pragma unroll
    for (int n = 0; n < 8; ++n) acc[n] = (f4v){0.f, 0.f, 0.f, 0.f};

#pragma unroll
    for (int n = 0; n < 8; ++n) {
      // hi batch of 4, then lo batch of 4 (halves live B-fragment regs)
      s8v bf[4];
#pragma unroll
      for (int c = 0; c < 4; ++c) {
        int ch = (c * 4 + kg) ^ (r16 & 7);
        bf[c] = *(const s8v*)&wt[(n * 16 + r16) * 128 + ch * 8];
      }
#pragma unroll
      for (int c = 0; c < 4; ++c)
        acc[n] = __builtin_amdgcn_mfma_f32_16x16x32_bf16(bf[c], afr[c], acc[n], 0, 0, 0);
#pragma unroll
      for (int c = 0; c < 4; ++c) {
        int ch = (c * 4 + kg) ^ (r16 & 7);
        bf[c] = *(const s8v*)&wt[(128 + n * 16 + r16) * 128 + ch * 8];
      }
#pragma unroll
      for (int c = 0; c < 4; ++c)
        acc[n] = __builtin_amdgcn_mfma_f32_16x16x32_bf16(bf[c], afr[c], acc[n], 0, 0, 0);
    }

    // epilogue burst: lane owns node tile*16+r16, features n*16 + kg*4 + {0..3}
    {
      int node = tile * 16 + r16;
      unsigned short* hp = Hb + (size_t)node * FD + kg * 4;
#pragma unroll
      for (int n = 0; n < 8; ++n) {
        uint2 v = make_uint2(pack2(acc[n][0], acc[n][1]), pack2(acc[n][2], acc[n][3]));
        *(uint2*)(hp + n * 16) = v;
      }
    }

    // rotate prefetch
    if (F32A) {
#pragma unroll
      for (int c = 0; c < 8; ++c) curF[c] = nxtF[c];
    } else {
#pragma unroll
      for (int c = 0; c < 4; ++c) curB[c] = nxtB[c];
    }
    tile = next;
  }
}

// ---------------- aggregation: 4 nodes per wave (16-lane quarters), uint4 lanes ----------------
// CSR segments padded to multiples of 4 -> branch-free 4-unrolled loop.
// 16 gathers in flight per wave (4 chains x 4-deep).
__global__ __launch_bounds__(256) void k_agg(const uint4* __restrict__ H4,
                                             const int* __restrict__ indptr,
                                             const uint2* __restrict__ edges,
                                             const float* __restrict__ dinv,
                                             const float* __restrict__ bias,
                                             uint4* __restrict__ out4, int relu) {
  int wid = (blockIdx.x * 256 + threadIdx.x) >> 6;  // global wave id
  int ql = threadIdx.x & 15;                        // lane within quarter
  int n = wid * 4 + ((threadIdx.x >> 4) & 3);       // node of this quarter
  if (n >= NN) return;
  float dv = dinv[n];
  float s2 = dv * dv;
  uint4 u = H4[(size_t)n * 16 + ql];
  float a0 = s2 * bflo(u.x), a1 = s2 * bfhi(u.x);
  float a2 = s2 * bflo(u.y), a3 = s2 * bfhi(u.y);
  float a4 = s2 * bflo(u.z), a5 = s2 * bfhi(u.z);
  float a6 = s2 * bflo(u.w), a7 = s2 * bfhi(u.w);
  int e0 = indptr[n], e1 = indptr[n + 1];  // e1-e0 is a multiple of 4
  for (int e = e0; e < e1; e += 4) {
    uint2 q0 = edges[e], q1 = edges[e + 1], q2 = edges[e + 2], q3 = edges[e + 3];
    uint4 v0 = H4[(size_t)q0.x * 16 + ql];
    uint4 v1 = H4[(size_t)q1.x * 16 + ql];
    uint4 v2 = H4[(size_t)q2.x * 16 + ql];
    uint4 v3 = H4[(size_t)q3.x * 16 + ql];
    float w0 = __uint_as_float(q0.y), w1 = __uint_as_float(q1.y);
    float w2 = __uint_as_float(q2.y), w3 = __uint_as_float(q3.y);
    a0 += w0 * bflo(v0.x); a1 += w0 * bfhi(v0.x); a2 += w0 * bflo(v0.y); a3 += w0 * bfhi(v0.y);
    a4 += w0 * bflo(v0.z); a5 += w0 * bfhi(v0.z); a6 += w0 * bflo(v0.w); a7 += w0 * bfhi(v0.w);
    a0 += w1 * bflo(v1.x); a1 += w1 * bfhi(v1.x); a2 += w1 * bflo(v1.y); a3 += w1 * bfhi(v1.y);
    a4 += w1 * bflo(v1.z); a5 += w1 * bfhi(v1.z); a6 += w1 * bflo(v1.w); a7 += w1 * bfhi(v1.w);
    a0 += w2 * bflo(v2.x); a1 += w2 * bfhi(v2.x); a2 += w2 * bflo(v2.y); a3 += w2 * bfhi(v2.y);
    a4 += w2 * bflo(v2.z); a5 += w2 * bfhi(v2.z); a6 += w2 * bflo(v2.w); a7 += w2 * bfhi(v2.w);
    a0 += w3 * bflo(v3.x); a1 += w3 * bfhi(v3.x); a2 += w3 * bflo(v3.y); a3 += w3 * bfhi(v3.y);
    a4 += w3 * bflo(v3.z); a5 += w3 * bfhi(v3.z); a6 += w3 * bflo(v3.w); a7 += w3 * bfhi(v3.w);
  }
  a0 += bias[ql * 8];     a1 += bias[ql * 8 + 1];
  a2 += bias[ql * 8 + 2]; a3 += bias[ql * 8 + 3];
  a4 += bias[ql * 8 + 4]; a5 += bias[ql * 8 + 5];
  a6 += bias[ql * 8 + 6]; a7 += bias[ql * 8 + 7];
  if (relu) {
    a0 = fmaxf(a0, 0.f); a1 = fmaxf(a1, 0.f); a2 = fmaxf(a2, 0.f); a3 = fmaxf(a3, 0.f);
    a4 = fmaxf(a4, 0.f); a5 = fmaxf(a5, 0.f); a6 = fmaxf(a6, 0.f); a7 = fmaxf(a7, 0.f);
  }
  out4[(size_t)n * 16 + ql] =
      make_uint4(pack2(a0, a1), pack2(a2, a3), pack2(a4, a5), pack2(a6, a7));
}

// ---------------- mean pool: wave per 64-node chunk, lanes cover row as bf16x2 ----------------
#define PW 64  // nodes per wave
__global__ __launch_bounds__(256) void k_pool(const unsigned* __restrict__ H2,
                                              const int* __restrict__ batch,
                                              float* __restrict__ psum) {
  int wgl = (blockIdx.x * 256 + threadIdx.x) >> 6;  // global wave id
  int lane = threadIdx.x & 63;
  int n0 = wgl * PW;
  if (n0 >= NN) return;
  int n1 = n0 + PW; if (n1 > NN) n1 = NN;
  int g0 = batch[n0], g1 = batch[n1 - 1];
  float a0 = 0.f, a1 = 0.f;
  if (g0 == g1) {
    int n = n0;
    for (; n + 3 < n1; n += 4) {
      unsigned v0 = H2[(size_t)(n + 0) * 64 + lane];
      unsigned v1 = H2[(size_t)(n + 1) * 64 + lane];
      unsigned v2 = H2[(size_t)(n + 2) * 64 + lane];
      unsigned v3 = H2[(size_t)(n + 3) * 64 + lane];
      a0 += bflo(v0) + bflo(v1) + bflo(v2) + bflo(v3);
      a1 += bfhi(v0) + bfhi(v1) + bfhi(v2) + bfhi(v3);
    }
    for (; n < n1; ++n) {
      unsigned v = H2[(size_t)n * 64 + lane];
      a0 += bflo(v); a1 += bfhi(v);
    }
    atomicAdd(&psum[g0 * FD + lane * 2], a0);
    atomicAdd(&psum[g0 * FD + lane * 2 + 1], a1);
  } else {
    int g = g0;
    for (int n = n0; n < n1; ++n) {
      int gn = batch[n];
      if (gn != g) {
        atomicAdd(&psum[g * FD + lane * 2], a0);
        atomicAdd(&psum[g * FD + lane * 2 + 1], a1);
        a0 = 0.f; a1 = 0.f; g = gn;
      }
      unsigned v = H2[(size_t)n * 64 + lane];
      a0 += bflo(v); a1 += bfhi(v);
    }
    atomicAdd(&psum[g * FD + lane * 2], a0);
    atomicAdd(&psum[g * FD + lane * 2 + 1], a1);
  }
}

__global__ void k_head(const float* __restrict__ psum, const int* __restrict__ starts,
                       const int* __restrict__ ends, const float* __restrict__ Wl,
                       const float* __restrict__ bl, float* __restrict__ out) {
  int t = threadIdx.x;  // 128 = 64 graphs x 2 classes
  int g = t >> 1, c = t & 1;
  int cnt = ends[g] - starts[g];
  if (cnt < 0) cnt = 0;
  float inv = 1.f / (float)(cnt > 0 ? cnt : 1);
  float acc = 0.f;
  for (int k = 0; k < FD; ++k) acc += psum[g * FD + k] * Wl[k * 2 + c];
  out[g * 2 + c] = acc * inv + bl[c];
}

// ---------------- host ----------------

extern "C" void kernel_launch(void* const* d_in, const int* in_sizes, int n_in,
                              void* d_out, int out_size, void* d_ws, size_t ws_size,
                              hipStream_t stream) {
  const float* x  = (const float*)d_in[0];
  const int* ei   = (const int*)d_in[1];
  const int* bat  = (const int*)d_in[2];
  const float* W1 = (const float*)d_in[3];
  const float* b1 = (const float*)d_in[4];
  const float* W2 = (const float*)d_in[5];
  const float* b2 = (const float*)d_in[6];
  const float* W3 = (const float*)d_in[7];
  const float* b3 = (const float*)d_in[8];
  const float* Wl = (const float*)d_in[9];
  const float* bl = (const float*)d_in[10];
  float* out = (float*)d_out;

  char* ws = (char*)d_ws;
  size_t off = 0;
  auto alloc = [&](size_t bytes) {
    void* p = ws + off;
    off += (bytes + 255) & ~(size_t)255;
    return p;
  };
  int* counts  = (int*)alloc(NN * 4);
  int* cursor  = (int*)alloc(NN * 4);
  int* indptr  = (int*)alloc((NN + 1) * 4);
  float* dinv  = (float*)alloc(NN * 4);
  int* bsum    = (int*)alloc(NB * 4);
  int* eb      = (int*)alloc(NB * 4);
  int* starts  = (int*)alloc(NG * 4);
  int* ends    = (int*)alloc(NG * 4);
  float* psum  = (float*)alloc(NG * FD * 4);
  uint2* edges = (uint2*)alloc((size_t)EPAD * 8);
  unsigned short* Hb   = (unsigned short*)alloc((size_t)NN * FD * 2);
  unsigned short* Abuf = (unsigned short*)alloc((size_t)NN * FD * 2);
  unsigned short* WTh  = (unsigned short*)alloc(3 * FD * FD * 2);
  unsigned short* WTl  = (unsigned short*)alloc(3 * FD * FD * 2);

  const int* row = ei;
  const int* col = ei + NE;

  // counts + cursor are adjacent in ws: single memset covers both (and the pad gap)
  hipMemsetAsync(counts, 0, (size_t)((char*)cursor - (char*)counts) + NN * 4, stream);
  hipMemsetAsync(edges, 0, (size_t)EPAD * 8, stream);
  k_init<<<32, 256, 0, stream>>>(psum);
  k_castW3<<<(3 * FD * FD + 255) / 256, 256, 0, stream>>>(W1, W2, W3, WTh, WTl);
  k_ranges<<<(NN + 255) / 256, 256, 0, stream>>>(bat, starts, ends);
  k_count<<<(NE + 255) / 256, 256, 0, stream>>>(col, counts);
  k_dinv<<<(NN + 255) / 256, 256, 0, stream>>>(counts, dinv);
  k_bsum<<<NB, 1024, 0, stream>>>(counts, bsum);
  k_bscan<<<1, 128, 0, stream>>>(bsum, eb);
  k_scan2<<<NB, 1024, 0, stream>>>(counts, eb, indptr);
  k_fill<<<(NE + 255) / 256, 256, 0, stream>>>(row, col, indptr, cursor, dinv, edges);

  int aggGrid = (NN + 15) / 16;       // 16 nodes per block (4 per wave x 4 waves)
  int poolGrid = ((NN + PW - 1) / PW * 64 + 255) / 256;

  k_gemm<1><<<GEMM_BLOCKS, 512, 0, stream>>>(x, WTh, WTl, Hb);
  k_agg<<<aggGrid, 256, 0, stream>>>((const uint4*)Hb, indptr, edges, dinv, b1,
                                     (uint4*)Abuf, 1);
  k_gemm<0><<<GEMM_BLOCKS, 512, 0, stream>>>(Abuf, WTh + FD * FD, WTl + FD * FD, Hb);
  k_agg<<<aggGrid, 256, 0, stream>>>((const uint4*)Hb, indptr, edges, dinv, b2,
                                     (uint4*)Abuf, 1);
  k_gemm<0><<<GEMM_BLOCKS, 512, 0, stream>>>(Abuf, WTh + 2 * FD * FD, WTl + 2 * FD * FD, Hb);
  k_agg<<<aggGrid, 256, 0, stream>>>((const uint4*)Hb, indptr, edges, dinv, b3,
                                     (uint4*)Abuf, 0);

  k_pool<<<poolGrid, 256, 0, stream>>>((const unsigned*)Abuf, bat, psum);
  k_head<<<1, 128, 0, stream>>>(psum, starts, ends, Wl, bl, out);
}

// Round 15
// 264.325 us; speedup vs baseline: 1.3118x; 1.3118x over previous
//
#include <hip/hip_runtime.h>

#define NN 100000
#define NE 600000
#define NG 64
#define FD 128
#define NB 98   // scan blocks of 1024: 98*1024 >= NN
#define EPAD 900000  // padded edge capacity: NE + 3*NN
#define NTILE16 6250   // 100000 / 16 row-tiles
#define GEMM_BLOCKS 512   // 2 blocks/CU (64 KB LDS each), 4 waves/block

typedef __attribute__((ext_vector_type(8))) short s8v;
typedef __attribute__((ext_vector_type(4))) float f4v;

__device__ inline float bflo(unsigned u) { return __uint_as_float(u << 16); }
__device__ inline float bfhi(unsigned u) { return __uint_as_float(u & 0xFFFF0000u); }
__device__ inline unsigned f2bfbits(float f) {  // round-to-nearest-even
  unsigned x = __float_as_uint(f);
  return (x + 0x7FFFu + ((x >> 16) & 1u)) >> 16;
}
__device__ inline unsigned pack2(float a, float b) { return f2bfbits(a) | (f2bfbits(b) << 16); }

// ---------------- weight cast: W f32 [K][N] -> WThi/WTlo bf16 [N][K], 3 weights in one ----------------
__global__ void k_castW3(const float* __restrict__ W1, const float* __restrict__ W2,
                         const float* __restrict__ W3, unsigned short* __restrict__ WTh,
                         unsigned short* __restrict__ WTl) {
  int e = blockIdx.x * 256 + threadIdx.x;   // grid covers 3*FD*FD
  int which = e / (FD * FD);
  int r = e - which * (FD * FD);
  if (which >= 3) return;
  const float* W = which == 0 ? W1 : (which == 1 ? W2 : W3);
  int k = r >> 7, n = r & 127;
  float v = W[r];
  unsigned hb = f2bfbits(v);
  float hf = __uint_as_float(hb << 16);
  unsigned lb = f2bfbits(v - hf);
  WTh[which * FD * FD + n * FD + k] = (unsigned short)hb;
  WTl[which * FD * FD + n * FD + k] = (unsigned short)lb;
}

// ---------------- degree / CSR build ----------------

__global__ void k_init(float* psum) {
  int i = blockIdx.x * 256 + threadIdx.x;
  if (i < NG * FD) psum[i] = 0.f;
}

__global__ void k_count(const int* __restrict__ col, int* __restrict__ counts) {
  int e = blockIdx.x * 256 + threadIdx.x;
  if (e < NE) atomicAdd(&counts[col[e]], 1);
}

__global__ void k_dinv(const int* __restrict__ counts, float* __restrict__ dinv) {
  int n = blockIdx.x * 256 + threadIdx.x;
  if (n < NN) dinv[n] = rsqrtf((float)counts[n] + 1.0f);
}

// 3-phase scan over PADDED counts: ceil(deg/4)*4 per node
__global__ void k_bsum(const int* __restrict__ counts, int* __restrict__ bsum) {
  __shared__ int wsm[16];
  int b = blockIdx.x, t = threadIdx.x;
  int i = b * 1024 + t;
  int x = (i < NN) ? ((counts[i] + 3) & ~3) : 0;
#pragma unroll
  for (int d = 32; d; d >>= 1) x += __shfl_down(x, d);
  if ((t & 63) == 0) wsm[t >> 6] = x;
  __syncthreads();
  if (t < 16) {
    int s = wsm[t];
#pragma unroll
    for (int d = 8; d; d >>= 1) s += __shfl_down(s, d);
    if (t == 0) bsum[b] = s;
  }
}

__global__ void k_bscan(const int* __restrict__ bsum, int* __restrict__ eb) {
  __shared__ int w0;
  int t = threadIdx.x;  // 128
  int x = (t < NB) ? bsum[t] : 0;
  int lane = t & 63;
  int inc = x;
#pragma unroll
  for (int d = 1; d < 64; d <<= 1) { int y = __shfl_up(inc, d); if (lane >= d) inc += y; }
  if (t == 63) w0 = inc;
  __syncthreads();
  int off = (t >= 64) ? w0 : 0;
  if (t < NB) eb[t] = off + inc - x;  // exclusive
}

__global__ void k_scan2(const int* __restrict__ counts, const int* __restrict__ eb,
                        int* __restrict__ indptr) {
  __shared__ int wsm[16];
  int b = blockIdx.x, t = threadIdx.x;
  int i = b * 1024 + t;
  int x = (i < NN) ? ((counts[i] + 3) & ~3) : 0;
  int lane = t & 63, wid = t >> 6;
  int inc = x;
#pragma unroll
  for (int d = 1; d < 64; d <<= 1) { int y = __shfl_up(inc, d); if (lane >= d) inc += y; }
  if (lane == 63) wsm[wid] = inc;
  __syncthreads();
  if (wid == 0) {
    int s = (lane < 16) ? wsm[lane] : 0;
#pragma unroll
    for (int d = 1; d < 16; d <<= 1) { int y = __shfl_up(s, d); if (lane >= d) s += y; }
    if (lane < 16) wsm[lane] = s;
  }
  __syncthreads();
  int woff = wid ? wsm[wid - 1] : 0;
  if (i < NN) indptr[i + 1] = eb[b] + woff + inc;
  if (i == 0) indptr[0] = 0;
}

// combined edge record: {src, nrm}; pad slots stay {0, 0.0f} from memset (exact no-ops)
__global__ void k_fill(const int* __restrict__ row, const int* __restrict__ col,
                       const int* __restrict__ indptr, int* __restrict__ cursor,
                       const float* __restrict__ dinv, uint2* __restrict__ edges) {
  int e = blockIdx.x * 256 + threadIdx.x;
  if (e >= NE) return;
  int c = col[e], r = row[e];
  int p = indptr[c] + atomicAdd(&cursor[c], 1);
  edges[p] = make_uint2((unsigned)r, __float_as_uint(dinv[r] * dinv[c]));
}

// batch is sorted: ranges by boundary detection
__global__ void k_ranges(const int* __restrict__ batch, int* __restrict__ starts,
                         int* __restrict__ ends) {
  int n = blockIdx.x * 256 + threadIdx.x;
  if (n >= NN) return;
  int g = batch[n];
  if (n == 0) {
    starts[g] = 0;
    for (int q = 0; q < g; ++q) { starts[q] = 0; ends[q] = 0; }
  } else {
    int gp = batch[n - 1];
    if (gp != g) {
      ends[gp] = n;
      starts[g] = n;
      for (int q = gp + 1; q < g; ++q) { starts[q] = n; ends[q] = n; }
    }
  }
  if (n == NN - 1) {
    ends[g] = NN;
    for (int q = g + 1; q < NG; ++q) { starts[q] = NN; ends[q] = NN; }
  }
}

// ---------------- MFMA GEMM: Hb[M,128] = A[M,128] @ (WThi+WTlo)^T ----------------
// R13's exact champion: 256-thread blocks, plain __launch_bounds__(256) — no
// VGPR cap (512-thread blocks cap at 128 and spill: R14's WRITE=94 MB; this
// regime writes clean 25 MB). W staged once in 64 KB LDS (XOR-swizzled, one
// barrier), barrier-free persistent loop over 16-row tiles, swapped MFMA
// operands, one-tile-ahead A prefetch, uint2 burst epilogue.
template <int F32A>
__global__ __launch_bounds__(256) void k_gemm(const void* __restrict__ Aab,
                                              const unsigned short* __restrict__ WThi,
                                              const unsigned short* __restrict__ WTlo,
                                              unsigned short* __restrict__ Hb) {
  __shared__ unsigned short wt[256 * 128];  // rows 0..127 = hi, 128..255 = lo
  int t = threadIdx.x, lane = t & 63, w = t >> 6;
  int r16 = lane & 15, kg = lane >> 4;

  {  // stage: thread t stages row t (16 chunks of 8 us), swizzled ch = j ^ (row&7)
    const unsigned short* src = (t < 128) ? (WThi + t * FD) : (WTlo + (t - 128) * FD);
#pragma unroll
    for (int j = 0; j < 16; ++j) {
      int ch = j ^ (t & 7);
      *(s8v*)&wt[t * 128 + ch * 8] = *(const s8v*)(src + j * 8);
    }
  }
  __syncthreads();

  const int stride = GEMM_BLOCKS * 4;
  int tile = blockIdx.x * 4 + w;   // 2048 waves over 6250 tiles (~3 each)

  // raw A prefetch registers (current / next)
  float4 curF[8], nxtF[8];
  s8v curB[4], nxtB[4];

  {  // load current tile's A (raw)
    int ar = tile * 16 + r16;
    if (F32A) {
      const float* ap = (const float*)Aab + (size_t)ar * FD + kg * 8;
#pragma unroll
      for (int c = 0; c < 4; ++c) {
        curF[c * 2] = *(const float4*)(ap + c * 32);
        curF[c * 2 + 1] = *(const float4*)(ap + c * 32 + 4);
      }
    } else {
      const unsigned short* ap = (const unsigned short*)Aab + (size_t)ar * FD + kg * 8;
#pragma unroll
      for (int c = 0; c < 4; ++c) curB[c] = *(const s8v*)(ap + c * 32);
    }
  }

  while (tile < NTILE16) {
    int next = tile + stride;
    int nld = (next < NTILE16) ? next : tile;  // dummy reload on last iter

    {  // issue next tile's A loads now — they complete under this tile's compute
      int ar = nld * 16 + r16;
      if (F32A) {
        const float* ap = (const float*)Aab + (size_t)ar * FD + kg * 8;
#pragma unroll
        for (int c = 0; c < 4; ++c) {
          nxtF[c * 2] = *(const float4*)(ap + c * 32);
          nxtF[c * 2 + 1] = *(const float4*)(ap + c * 32 + 4);
        }
      } else {
        const unsigned short* ap = (const unsigned short*)Aab + (size_t)ar * FD + kg * 8;
#pragma unroll
        for (int c = 0; c < 4; ++c) nxtB[c] = *(const s8v*)(ap + c * 32);
      }
    }

    // convert current raw A -> bf16 fragments
    s8v afr[4];
    if (F32A) {
#pragma unroll
      for (int c = 0; c < 4; ++c) {
        float4 p0 = curF[c * 2], p1 = curF[c * 2 + 1];
        s8v f;
        f[0] = (short)f2bfbits(p0.x); f[1] = (short)f2bfbits(p0.y);
        f[2] = (short)f2bfbits(p0.z); f[3] = (short)f2bfbits(p0.w);
        f[4] = (short)f2bfbits(p1.x); f[5] = (short)f2bfbits(p1.y);
        f[6] = (short)f2bfbits(p1.z); f[7] = (short)f2bfbits(p1.w);
        afr[c] = f;
      }
    } else {
#pragma unroll
      for (int c = 0; c < 4; ++c) afr[c] = curB[c];
    }

    f4v acc[8];
#pragma unroll
    for (int n = 0; n < 8; ++n) acc[n] = (f4v){0.f, 0.f, 0.f, 0.f};

#pragma unroll
    for (int n = 0; n < 8; ++n) {
      s8v bh[4], bl[4];
#pragma unroll
      for (int c = 0; c < 4; ++c) {
        int ch = (c * 4 + kg) ^ (r16 & 7);
        bh[c] = *(const s8v*)&wt[(n * 16 + r16) * 128 + ch * 8];
        bl[c] = *(const s8v*)&wt[(128 + n * 16 + r16) * 128 + ch * 8];
      }
      // swapped operands: W-fragment as A-operand -> D col = node, D row = feature
#pragma unroll
      for (int c = 0; c < 4; ++c)
        acc[n] = __builtin_amdgcn_mfma_f32_16x16x32_bf16(bh[c], afr[c], acc[n], 0, 0, 0);
#pragma unroll
      for (int c = 0; c < 4; ++c)
        acc[n] = __builtin_amdgcn_mfma_f32_16x16x32_bf16(bl[c], afr[c], acc[n], 0, 0, 0);
    }

    // epilogue burst: lane owns node tile*16+r16, features n*16 + kg*4 + {0..3}
    {
      int node = tile * 16 + r16;
      unsigned short* hp = Hb + (size_t)node * FD + kg * 4;
#pragma unroll
      for (int n = 0; n < 8; ++n) {
        uint2 v = make_uint2(pack2(acc[n][0], acc[n][1]), pack2(acc[n][2], acc[n][3]));
        *(uint2*)(hp + n * 16) = v;
      }
    }

    // rotate prefetch
    if (F32A) {
#pragma unroll
      for (int c = 0; c < 8; ++c) curF[c] = nxtF[c];
    } else {
#pragma unroll
      for (int c = 0; c < 4; ++c) curB[c] = nxtB[c];
    }
    tile = next;
  }
}

// ---------------- aggregation: 4 nodes per wave (16-lane quarters), uint4 lanes ----------------
// CSR segments padded to multiples of 4 -> branch-free 4-unrolled loop.
// 16 gathers in flight per wave (4 chains x 4-deep).
__global__ __launch_bounds__(256) void k_agg(const uint4* __restrict__ H4,
                                             const int* __restrict__ indptr,
                                             const uint2* __restrict__ edges,
                                             const float* __restrict__ dinv,
                                             const float* __restrict__ bias,
                                             uint4* __restrict__ out4, int relu) {
  int wid = (blockIdx.x * 256 + threadIdx.x) >> 6;  // global wave id
  int ql = threadIdx.x & 15;                        // lane within quarter
  int n = wid * 4 + ((threadIdx.x >> 4) & 3);       // node of this quarter
  if (n >= NN) return;
  float dv = dinv[n];
  float s2 = dv * dv;
  uint4 u = H4[(size_t)n * 16 + ql];
  float a0 = s2 * bflo(u.x), a1 = s2 * bfhi(u.x);
  float a2 = s2 * bflo(u.y), a3 = s2 * bfhi(u.y);
  float a4 = s2 * bflo(u.z), a5 = s2 * bfhi(u.z);
  float a6 = s2 * bflo(u.w), a7 = s2 * bfhi(u.w);
  int e0 = indptr[n], e1 = indptr[n + 1];  // e1-e0 is a multiple of 4
  for (int e = e0; e < e1; e += 4) {
    uint2 q0 = edges[e], q1 = edges[e + 1], q2 = edges[e + 2], q3 = edges[e + 3];
    uint4 v0 = H4[(size_t)q0.x * 16 + ql];
    uint4 v1 = H4[(size_t)q1.x * 16 + ql];
    uint4 v2 = H4[(size_t)q2.x * 16 + ql];
    uint4 v3 = H4[(size_t)q3.x * 16 + ql];
    float w0 = __uint_as_float(q0.y), w1 = __uint_as_float(q1.y);
    float w2 = __uint_as_float(q2.y), w3 = __uint_as_float(q3.y);
    a0 += w0 * bflo(v0.x); a1 += w0 * bfhi(v0.x); a2 += w0 * bflo(v0.y); a3 += w0 * bfhi(v0.y);
    a4 += w0 * bflo(v0.z); a5 += w0 * bfhi(v0.z); a6 += w0 * bflo(v0.w); a7 += w0 * bfhi(v0.w);
    a0 += w1 * bflo(v1.x); a1 += w1 * bfhi(v1.x); a2 += w1 * bflo(v1.y); a3 += w1 * bfhi(v1.y);
    a4 += w1 * bflo(v1.z); a5 += w1 * bfhi(v1.z); a6 += w1 * bflo(v1.w); a7 += w1 * bfhi(v1.w);
    a0 += w2 * bflo(v2.x); a1 += w2 * bfhi(v2.x); a2 += w2 * bflo(v2.y); a3 += w2 * bfhi(v2.y);
    a4 += w2 * bflo(v2.z); a5 += w2 * bfhi(v2.z); a6 += w2 * bflo(v2.w); a7 += w2 * bfhi(v2.w);
    a0 += w3 * bflo(v3.x); a1 += w3 * bfhi(v3.x); a2 += w3 * bflo(v3.y); a3 += w3 * bfhi(v3.y);
    a4 += w3 * bflo(v3.z); a5 += w3 * bfhi(v3.z); a6 += w3 * bflo(v3.w); a7 += w3 * bfhi(v3.w);
  }
  a0 += bias[ql * 8];     a1 += bias[ql * 8 + 1];
  a2 += bias[ql * 8 + 2]; a3 += bias[ql * 8 + 3];
  a4 += bias[ql * 8 + 4]; a5 += bias[ql * 8 + 5];
  a6 += bias[ql * 8 + 6]; a7 += bias[ql * 8 + 7];
  if (relu) {
    a0 = fmaxf(a0, 0.f); a1 = fmaxf(a1, 0.f); a2 = fmaxf(a2, 0.f); a3 = fmaxf(a3, 0.f);
    a4 = fmaxf(a4, 0.f); a5 = fmaxf(a5, 0.f); a6 = fmaxf(a6, 0.f); a7 = fmaxf(a7, 0.f);
  }
  out4[(size_t)n * 16 + ql] =
      make_uint4(pack2(a0, a1), pack2(a2, a3), pack2(a4, a5), pack2(a6, a7));
}

// ---------------- mean pool: wave per 64-node chunk, lanes cover row as bf16x2 ----------------
#define PW 64  // nodes per wave
__global__ __launch_bounds__(256) void k_pool(const unsigned* __restrict__ H2,
                                              const int* __restrict__ batch,
                                              float* __restrict__ psum) {
  int wgl = (blockIdx.x * 256 + threadIdx.x) >> 6;  // global wave id
  int lane = threadIdx.x & 63;
  int n0 = wgl * PW;
  if (n0 >= NN) return;
  int n1 = n0 + PW; if (n1 > NN) n1 = NN;
  int g0 = batch[n0], g1 = batch[n1 - 1];
  float a0 = 0.f, a1 = 0.f;
  if (g0 == g1) {
    int n = n0;
    for (; n + 3 < n1; n += 4) {
      unsigned v0 = H2[(size_t)(n + 0) * 64 + lane];
      unsigned v1 = H2[(size_t)(n + 1) * 64 + lane];
      unsigned v2 = H2[(size_t)(n + 2) * 64 + lane];
      unsigned v3 = H2[(size_t)(n + 3) * 64 + lane];
      a0 += bflo(v0) + bflo(v1) + bflo(v2) + bflo(v3);
      a1 += bfhi(v0) + bfhi(v1) + bfhi(v2) + bfhi(v3);
    }
    for (; n < n1; ++n) {
      unsigned v = H2[(size_t)n * 64 + lane];
      a0 += bflo(v); a1 += bfhi(v);
    }
    atomicAdd(&psum[g0 * FD + lane * 2], a0);
    atomicAdd(&psum[g0 * FD + lane * 2 + 1], a1);
  } else {
    int g = g0;
    for (int n = n0; n < n1; ++n) {
      int gn = batch[n];
      if (gn != g) {
        atomicAdd(&psum[g * FD + lane * 2], a0);
        atomicAdd(&psum[g * FD + lane * 2 + 1], a1);
        a0 = 0.f; a1 = 0.f; g = gn;
      }
      unsigned v = H2[(size_t)n * 64 + lane];
      a0 += bflo(v); a1 += bfhi(v);
    }
    atomicAdd(&psum[g * FD + lane * 2], a0);
    atomicAdd(&psum[g * FD + lane * 2 + 1], a1);
  }
}

__global__ void k_head(const float* __restrict__ psum, const int* __restrict__ starts,
                       const int* __restrict__ ends, const float* __restrict__ Wl,
                       const float* __restrict__ bl, float* __restrict__ out) {
  int t = threadIdx.x;  // 128 = 64 graphs x 2 classes
  int g = t >> 1, c = t & 1;
  int cnt = ends[g] - starts[g];
  if (cnt < 0) cnt = 0;
  float inv = 1.f / (float)(cnt > 0 ? cnt : 1);
  float acc = 0.f;
  for (int k = 0; k < FD; ++k) acc += psum[g * FD + k] * Wl[k * 2 + c];
  out[g * 2 + c] = acc * inv + bl[c];
}

// ---------------- host ----------------

extern "C" void kernel_launch(void* const* d_in, const int* in_sizes, int n_in,
                              void* d_out, int out_size, void* d_ws, size_t ws_size,
                              hipStream_t stream) {
  const float* x  = (const float*)d_in[0];
  const int* ei   = (const int*)d_in[1];
  const int* bat  = (const int*)d_in[2];
  const float* W1 = (const float*)d_in[3];
  const float* b1 = (const float*)d_in[4];
  const float* W2 = (const float*)d_in[5];
  const float* b2 = (const float*)d_in[6];
  const float* W3 = (const float*)d_in[7];
  const float* b3 = (const float*)d_in[8];
  const float* Wl = (const float*)d_in[9];
  const float* bl = (const float*)d_in[10];
  float* out = (float*)d_out;

  char* ws = (char*)d_ws;
  size_t off = 0;
  auto alloc = [&](size_t bytes) {
    void* p = ws + off;
    off += (bytes + 255) & ~(size_t)255;
    return p;
  };
  int* counts  = (int*)alloc(NN * 4);
  int* cursor  = (int*)alloc(NN * 4);
  int* indptr  = (int*)alloc((NN + 1) * 4);
  float* dinv  = (float*)alloc(NN * 4);
  int* bsum    = (int*)alloc(NB * 4);
  int* eb      = (int*)alloc(NB * 4);
  int* starts  = (int*)alloc(NG * 4);
  int* ends    = (int*)alloc(NG * 4);
  float* psum  = (float*)alloc(NG * FD * 4);
  uint2* edges = (uint2*)alloc((size_t)EPAD * 8);
  unsigned short* Hb   = (unsigned short*)alloc((size_t)NN * FD * 2);
  unsigned short* Abuf = (unsigned short*)alloc((size_t)NN * FD * 2);
  unsigned short* WTh  = (unsigned short*)alloc(3 * FD * FD * 2);
  unsigned short* WTl  = (unsigned short*)alloc(3 * FD * FD * 2);

  const int* row = ei;
  const int* col = ei + NE;

  // counts + cursor are adjacent in ws: single memset covers both (and the pad gap)
  hipMemsetAsync(counts, 0, (size_t)((char*)cursor - (char*)counts) + NN * 4, stream);
  hipMemsetAsync(edges, 0, (size_t)EPAD * 8, stream);
  k_init<<<32, 256, 0, stream>>>(psum);
  k_castW3<<<(3 * FD * FD + 255) / 256, 256, 0, stream>>>(W1, W2, W3, WTh, WTl);
  k_ranges<<<(NN + 255) / 256, 256, 0, stream>>>(bat, starts, ends);
  k_count<<<(NE + 255) / 256, 256, 0, stream>>>(col, counts);
  k_dinv<<<(NN + 255) / 256, 256, 0, stream>>>(counts, dinv);
  k_bsum<<<NB, 1024, 0, stream>>>(counts, bsum);
  k_bscan<<<1, 128, 0, stream>>>(bsum, eb);
  k_scan2<<<NB, 1024, 0, stream>>>(counts, eb, indptr);
  k_fill<<<(NE + 255) / 256, 256, 0, stream>>>(row, col, indptr, cursor, dinv, edges);

  int aggGrid = (NN + 15) / 16;       // 16 nodes per block (4 per wave x 4 waves)
  int poolGrid = ((NN + PW - 1) / PW * 64 + 255) / 256;

  k_gemm<1><<<GEMM_BLOCKS, 256, 0, stream>>>(x, WTh, WTl, Hb);
  k_agg<<<aggGrid, 256, 0, stream>>>((const uint4*)Hb, indptr, edges, dinv, b1,
                                     (uint4*)Abuf, 1);
  k_gemm<0><<<GEMM_BLOCKS, 256, 0, stream>>>(Abuf, WTh + FD * FD, WTl + FD * FD, Hb);
  k_agg<<<aggGrid, 256, 0, stream>>>((const uint4*)Hb, indptr, edges, dinv, b2,
                                     (uint4*)Abuf, 1);
  k_gemm<0><<<GEMM_BLOCKS, 256, 0, stream>>>(Abuf, WTh + 2 * FD * FD, WTl + 2 * FD * FD, Hb);
  k_agg<<<aggGrid, 256, 0, stream>>>((const uint4*)Hb, indptr, edges, dinv, b3,
                                     (uint4*)Abuf, 0);

  k_pool<<<poolGrid, 256, 0, stream>>>((const unsigned*)Abuf, bat, psum);
  k_head<<<1, 128, 0, stream>>>(psum, starts, ends, Wl, bl, out);
}

// Round 16
// 256.147 us; speedup vs baseline: 1.3537x; 1.0319x over previous
//
#include <hip/hip_runtime.h>

#define NN 100000
#define NE 600000
#define NG 64
#define FD 128
#define NB 98   // scan blocks of 1024: 98*1024 >= NN
#define EPAD 900000  // padded edge capacity: NE + 3*NN
#define GEMM_BLOCKS 512   // 2 blocks/CU (64 KB LDS each), 4 waves/block

typedef __attribute__((ext_vector_type(8))) short s8v;
typedef __attribute__((ext_vector_type(4))) float f4v;

__device__ inline float bflo(unsigned u) { return __uint_as_float(u << 16); }
__device__ inline float bfhi(unsigned u) { return __uint_as_float(u & 0xFFFF0000u); }
__device__ inline unsigned f2bfbits(float f) {  // round-to-nearest-even
  unsigned x = __float_as_uint(f);
  return (x + 0x7FFFu + ((x >> 16) & 1u)) >> 16;
}
__device__ inline unsigned pack2(float a, float b) { return f2bfbits(a) | (f2bfbits(b) << 16); }

// ---------------- fused prep: psum init + W casts + graph ranges ----------------
// grid covers NN threads; sub-ranges also do castW3 (3*FD*FD) and psum init.
__global__ void k_prep(const float* __restrict__ W1, const float* __restrict__ W2,
                       const float* __restrict__ W3, unsigned short* __restrict__ WTh,
                       unsigned short* __restrict__ WTl, float* __restrict__ psum,
                       const int* __restrict__ batch, int* __restrict__ starts,
                       int* __restrict__ ends) {
  int tid = blockIdx.x * 256 + threadIdx.x;
  if (tid < NG * FD) psum[tid] = 0.f;
  if (tid < 3 * FD * FD) {
    int which = tid / (FD * FD);
    int r = tid - which * (FD * FD);
    const float* W = which == 0 ? W1 : (which == 1 ? W2 : W3);
    int k = r >> 7, n = r & 127;
    float v = W[r];
    unsigned hb = f2bfbits(v);
    float hf = __uint_as_float(hb << 16);
    unsigned lb = f2bfbits(v - hf);
    WTh[which * FD * FD + n * FD + k] = (unsigned short)hb;
    WTl[which * FD * FD + n * FD + k] = (unsigned short)lb;
  }
  int n = tid;
  if (n >= NN) return;
  int g = batch[n];
  if (n == 0) {
    starts[g] = 0;
    for (int q = 0; q < g; ++q) { starts[q] = 0; ends[q] = 0; }
  } else {
    int gp = batch[n - 1];
    if (gp != g) {
      ends[gp] = n;
      starts[g] = n;
      for (int q = gp + 1; q < g; ++q) { starts[q] = n; ends[q] = n; }
    }
  }
  if (n == NN - 1) {
    ends[g] = NN;
    for (int q = g + 1; q < NG; ++q) { starts[q] = NN; ends[q] = NN; }
  }
}

// ---------------- degree / CSR build ----------------

__global__ void k_count(const int* __restrict__ col, int* __restrict__ counts) {
  int e = blockIdx.x * 256 + threadIdx.x;
  if (e < NE) atomicAdd(&counts[col[e]], 1);
}

// block sums over PADDED counts + dinv (fused: reads counts once anyway)
__global__ void k_bsum(const int* __restrict__ counts, int* __restrict__ bsum,
                       float* __restrict__ dinv) {
  __shared__ int wsm[16];
  int b = blockIdx.x, t = threadIdx.x;
  int i = b * 1024 + t;
  int c = (i < NN) ? counts[i] : 0;
  if (i < NN) dinv[i] = rsqrtf((float)c + 1.0f);
  int x = (i < NN) ? ((c + 3) & ~3) : 0;
#pragma unroll
  for (int d = 32; d; d >>= 1) x += __shfl_down(x, d);
  if ((t & 63) == 0) wsm[t >> 6] = x;
  __syncthreads();
  if (t < 16) {
    int s = wsm[t];
#pragma unroll
    for (int d = 8; d; d >>= 1) s += __shfl_down(s, d);
    if (t == 0) bsum[b] = s;
  }
}

__global__ void k_bscan(const int* __restrict__ bsum, int* __restrict__ eb) {
  __shared__ int w0;
  int t = threadIdx.x;  // 128
  int x = (t < NB) ? bsum[t] : 0;
  int lane = t & 63;
  int inc = x;
#pragma unroll
  for (int d = 1; d < 64; d <<= 1) { int y = __shfl_up(inc, d); if (lane >= d) inc += y; }
  if (t == 63) w0 = inc;
  __syncthreads();
  int off = (t >= 64) ? w0 : 0;
  if (t < NB) eb[t] = off + inc - x;  // exclusive
}

__global__ void k_scan2(const int* __restrict__ counts, const int* __restrict__ eb,
                        int* __restrict__ indptr) {
  __shared__ int wsm[16];
  int b = blockIdx.x, t = threadIdx.x;
  int i = b * 1024 + t;
  int x = (i < NN) ? ((counts[i] + 3) & ~3) : 0;
  int lane = t & 63, wid = t >> 6;
  int inc = x;
#pragma unroll
  for (int d = 1; d < 64; d <<= 1) { int y = __shfl_up(inc, d); if (lane >= d) inc += y; }
  if (lane == 63) wsm[wid] = inc;
  __syncthreads();
  if (wid == 0) {
    int s = (lane < 16) ? wsm[lane] : 0;
#pragma unroll
    for (int d = 1; d < 16; d <<= 1) { int y = __shfl_up(s, d); if (lane >= d) s += y; }
    if (lane < 16) wsm[lane] = s;
  }
  __syncthreads();
  int woff = wid ? wsm[wid - 1] : 0;
  if (i < NN) indptr[i + 1] = eb[b] + woff + inc;
  if (i == 0) indptr[0] = 0;
}

// combined edge record: {src, nrm}; pad slots stay {0, 0.0f} from memset (exact no-ops)
__global__ void k_fill(const int* __restrict__ row, const int* __restrict__ col,
                       const int* __restrict__ indptr, int* __restrict__ cursor,
                       const float* __restrict__ dinv, uint2* __restrict__ edges) {
  int e = blockIdx.x * 256 + threadIdx.x;
  if (e >= NE) return;
  int c = col[e], r = row[e];
  int p = indptr[c] + atomicAdd(&cursor[c], 1);
  edges[p] = make_uint2((unsigned)r, __float_as_uint(dinv[r] * dinv[c]));
}

// ---------------- MFMA GEMM: Hb[M,128] = A[M,128] @ (WThi+WTlo)^T ----------------
// 256-thread blocks, plain __launch_bounds__(256) — no VGPR cap (caps spill to
// scratch: R10-14 evidence). W staged once in 64 KB LDS (XOR-swizzled, one
// barrier), barrier-free persistent loop, swapped MFMA operands, one-tile-ahead
// A prefetch, uint2 burst epilogue. bf16 layers use 32-row tiles (RT=2): LDS
// already caps occupancy at 2 blocks/CU so the extra VGPR is free, and LDS
// reads per output node are halved (8 ds_reads feed 16 MFMAs per n).
template <int F32A>
__global__ __launch_bounds__(256) void k_gemm(const void* __restrict__ Aab,
                                              const unsigned short* __restrict__ WThi,
                                              const unsigned short* __restrict__ WTlo,
                                              unsigned short* __restrict__ Hb) {
  constexpr int RT = F32A ? 1 : 2;   // 16-row tiles per wave
  constexpr int ROWS = 16 * RT;
  constexpr int NTL = NN / ROWS;     // 6250 (f32) / 3125 (bf16)
  __shared__ unsigned short wt[256 * 128];  // rows 0..127 = hi, 128..255 = lo
  int t = threadIdx.x, lane = t & 63, w = t >> 6;
  int r16 = lane & 15, kg = lane >> 4;

  {  // stage: thread t stages row t (16 chunks of 8 us), swizzled ch = j ^ (row&7)
    const unsigned short* src = (t < 128) ? (WThi + t * FD) : (WTlo + (t - 128) * FD);
#pragma unroll
    for (int j = 0; j < 16; ++j) {
      int ch = j ^ (t & 7);
      *(s8v*)&wt[t * 128 + ch * 8] = *(const s8v*)(src + j * 8);
    }
  }
  __syncthreads();

  const int stride = GEMM_BLOCKS * 4;
  int tile = blockIdx.x * 4 + w;

  // raw A prefetch registers (current / next)
  float4 curF[8], nxtF[8];
  s8v curB[RT][4], nxtB[RT][4];

  if (tile < NTL) {  // load current tile's A (raw)
    if (F32A) {
      const float* ap = (const float*)Aab + (size_t)(tile * ROWS + r16) * FD + kg * 8;
#pragma unroll
      for (int c = 0; c < 4; ++c) {
        curF[c * 2] = *(const float4*)(ap + c * 32);
        curF[c * 2 + 1] = *(const float4*)(ap + c * 32 + 4);
      }
    } else {
#pragma unroll
      for (int rt = 0; rt < RT; ++rt) {
        const unsigned short* ap =
            (const unsigned short*)Aab + (size_t)(tile * ROWS + rt * 16 + r16) * FD + kg * 8;
#pragma unroll
        for (int c = 0; c < 4; ++c) curB[rt][c] = *(const s8v*)(ap + c * 32);
      }
    }
  }

  while (tile < NTL) {
    int next = tile + stride;
    int nld = (next < NTL) ? next : tile;  // dummy reload on last iter

    {  // issue next tile's A loads now — they complete under this tile's compute
      if (F32A) {
        const float* ap = (const float*)Aab + (size_t)(nld * ROWS + r16) * FD + kg * 8;
#pragma unroll
        for (int c = 0; c < 4; ++c) {
          nxtF[c * 2] = *(const float4*)(ap + c * 32);
          nxtF[c * 2 + 1] = *(const float4*)(ap + c * 32 + 4);
        }
      } else {
#pragma unroll
        for (int rt = 0; rt < RT; ++rt) {
          const unsigned short* ap =
              (const unsigned short*)Aab + (size_t)(nld * ROWS + rt * 16 + r16) * FD + kg * 8;
#pragma unroll
          for (int c = 0; c < 4; ++c) nxtB[rt][c] = *(const s8v*)(ap + c * 32);
        }
      }
    }

    // convert current raw A -> bf16 fragments
    s8v afr[RT][4];
    if (F32A) {
#pragma unroll
      for (int c = 0; c < 4; ++c) {
        float4 p0 = curF[c * 2], p1 = curF[c * 2 + 1];
        s8v f;
        f[0] = (short)f2bfbits(p0.x); f[1] = (short)f2bfbits(p0.y);
        f[2] = (short)f2bfbits(p0.z); f[3] = (short)f2bfbits(p0.w);
        f[4] = (short)f2bfbits(p1.x); f[5] = (short)f2bfbits(p1.y);
        f[6] = (short)f2bfbits(p1.z); f[7] = (short)f2bfbits(p1.w);
        afr[0][c] = f;
      }
    } else {
#pragma unroll
      for (int rt = 0; rt < RT; ++rt)
#pragma unroll
        for (int c = 0; c < 4; ++c) afr[rt][c] = curB[rt][c];
    }

    f4v acc[RT][8];
#pragma unroll
    for (int rt = 0; rt < RT; ++rt)
#pragma unroll
      for (int n = 0; n < 8; ++n) acc[rt][n] = (f4v){0.f, 0.f, 0.f, 0.f};

#pragma unroll
    for (int n = 0; n < 8; ++n) {
      s8v bh[4], bl[4];
#pragma unroll
      for (int c = 0; c < 4; ++c) {
        int ch = (c * 4 + kg) ^ (r16 & 7);
        bh[c] = *(const s8v*)&wt[(n * 16 + r16) * 128 + ch * 8];
        bl[c] = *(const s8v*)&wt[(128 + n * 16 + r16) * 128 + ch * 8];
      }
      // swapped operands: W-fragment as A-operand -> D col = node, D row = feature
      // per-node order is bh[0..3] then bl[0..3] — identical to R13/R15
#pragma unroll
      for (int c = 0; c < 4; ++c)
#pragma unroll
        for (int rt = 0; rt < RT; ++rt)
          acc[rt][n] = __builtin_amdgcn_mfma_f32_16x16x32_bf16(bh[c], afr[rt][c], acc[rt][n], 0, 0, 0);
#pragma unroll
      for (int c = 0; c < 4; ++c)
#pragma unroll
        for (int rt = 0; rt < RT; ++rt)
          acc[rt][n] = __builtin_amdgcn_mfma_f32_16x16x32_bf16(bl[c], afr[rt][c], acc[rt][n], 0, 0, 0);
    }

    // epilogue burst: lane owns node tile*ROWS + rt*16 + r16
#pragma unroll
    for (int rt = 0; rt < RT; ++rt) {
      int node = tile * ROWS + rt * 16 + r16;
      unsigned short* hp = Hb + (size_t)node * FD + kg * 4;
#pragma unroll
      for (int n = 0; n < 8; ++n) {
        uint2 v = make_uint2(pack2(acc[rt][n][0], acc[rt][n][1]),
                             pack2(acc[rt][n][2], acc[rt][n][3]));
        *(uint2*)(hp + n * 16) = v;
      }
    }

    // rotate prefetch
    if (F32A) {
#pragma unroll
      for (int c = 0; c < 8; ++c) curF[c] = nxtF[c];
    } else {
#pragma unroll
      for (int rt = 0; rt < RT; ++rt)
#pragma unroll
        for (int c = 0; c < 4; ++c) curB[rt][c] = nxtB[rt][c];
    }
    tile = next;
  }
}

// ---------------- aggregation: 4 nodes per wave (16-lane quarters), uint4 lanes ----------------
__global__ __launch_bounds__(256) void k_agg(const uint4* __restrict__ H4,
                                             const int* __restrict__ indptr,
                                             const uint2* __restrict__ edges,
                                             const float* __restrict__ dinv,
                                             const float* __restrict__ bias,
                                             uint4* __restrict__ out4, int relu) {
  int wid = (blockIdx.x * 256 + threadIdx.x) >> 6;  // global wave id
  int ql = threadIdx.x & 15;                        // lane within quarter
  int n = wid * 4 + ((threadIdx.x >> 4) & 3);       // node of this quarter
  if (n >= NN) return;
  float dv = dinv[n];
  float s2 = dv * dv;
  uint4 u = H4[(size_t)n * 16 + ql];
  float a0 = s2 * bflo(u.x), a1 = s2 * bfhi(u.x);
  float a2 = s2 * bflo(u.y), a3 = s2 * bfhi(u.y);
  float a4 = s2 * bflo(u.z), a5 = s2 * bfhi(u.z);
  float a6 = s2 * bflo(u.w), a7 = s2 * bfhi(u.w);
  int e0 = indptr[n], e1 = indptr[n + 1];  // e1-e0 is a multiple of 4
  for (int e = e0; e < e1; e += 4) {
    uint2 q0 = edges[e], q1 = edges[e + 1], q2 = edges[e + 2], q3 = edges[e + 3];
    uint4 v0 = H4[(size_t)q0.x * 16 + ql];
    uint4 v1 = H4[(size_t)q1.x * 16 + ql];
    uint4 v2 = H4[(size_t)q2.x * 16 + ql];
    uint4 v3 = H4[(size_t)q3.x * 16 + ql];
    float w0 = __uint_as_float(q0.y), w1 = __uint_as_float(q1.y);
    float w2 = __uint_as_float(q2.y), w3 = __uint_as_float(q3.y);
    a0 += w0 * bflo(v0.x); a1 += w0 * bfhi(v0.x); a2 += w0 * bflo(v0.y); a3 += w0 * bfhi(v0.y);
    a4 += w0 * bflo(v0.z); a5 += w0 * bfhi(v0.z); a6 += w0 * bflo(v0.w); a7 += w0 * bfhi(v0.w);
    a0 += w1 * bflo(v1.x); a1 += w1 * bfhi(v1.x); a2 += w1 * bflo(v1.y); a3 += w1 * bfhi(v1.y);
    a4 += w1 * bflo(v1.z); a5 += w1 * bfhi(v1.z); a6 += w1 * bflo(v1.w); a7 += w1 * bfhi(v1.w);
    a0 += w2 * bflo(v2.x); a1 += w2 * bfhi(v2.x); a2 += w2 * bflo(v2.y); a3 += w2 * bfhi(v2.y);
    a4 += w2 * bflo(v2.z); a5 += w2 * bfhi(v2.z); a6 += w2 * bflo(v2.w); a7 += w2 * bfhi(v2.w);
    a0 += w3 * bflo(v3.x); a1 += w3 * bfhi(v3.x); a2 += w3 * bflo(v3.y); a3 += w3 * bfhi(v3.y);
    a4 += w3 * bflo(v3.z); a5 += w3 * bfhi(v3.z); a6 += w3 * bflo(v3.w); a7 += w3 * bfhi(v3.w);
  }
  a0 += bias[ql * 8];     a1 += bias[ql * 8 + 1];
  a2 += bias[ql * 8 + 2]; a3 += bias[ql * 8 + 3];
  a4 += bias[ql * 8 + 4]; a5 += bias[ql * 8 + 5];
  a6 += bias[ql * 8 + 6]; a7 += bias[ql * 8 + 7];
  if (relu) {
    a0 = fmaxf(a0, 0.f); a1 = fmaxf(a1, 0.f); a2 = fmaxf(a2, 0.f); a3 = fmaxf(a3, 0.f);
    a4 = fmaxf(a4, 0.f); a5 = fmaxf(a5, 0.f); a6 = fmaxf(a6, 0.f); a7 = fmaxf(a7, 0.f);
  }
  out4[(size_t)n * 16 + ql] =
      make_uint4(pack2(a0, a1), pack2(a2, a3), pack2(a4, a5), pack2(a6, a7));
}

// ---------------- mean pool: wave per 64-node chunk, lanes cover row as bf16x2 ----------------
#define PW 64  // nodes per wave
__global__ __launch_bounds__(256) void k_pool(const unsigned* __restrict__ H2,
                                              const int* __restrict__ batch,
                                              float* __restrict__ psum) {
  int wgl = (blockIdx.x * 256 + threadIdx.x) >> 6;  // global wave id
  int lane = threadIdx.x & 63;
  int n0 = wgl * PW;
  if (n0 >= NN) return;
  int n1 = n0 + PW; if (n1 > NN) n1 = NN;
  int g0 = batch[n0], g1 = batch[n1 - 1];
  float a0 = 0.f, a1 = 0.f;
  if (g0 == g1) {
    int n = n0;
    for (; n + 3 < n1; n += 4) {
      unsigned v0 = H2[(size_t)(n + 0) * 64 + lane];
      unsigned v1 = H2[(size_t)(n + 1) * 64 + lane];
      unsigned v2 = H2[(size_t)(n + 2) * 64 + lane];
      unsigned v3 = H2[(size_t)(n + 3) * 64 + lane];
      a0 += bflo(v0) + bflo(v1) + bflo(v2) + bflo(v3);
      a1 += bfhi(v0) + bfhi(v1) + bfhi(v2) + bfhi(v3);
    }
    for (; n < n1; ++n) {
      unsigned v = H2[(size_t)n * 64 + lane];
      a0 += bflo(v); a1 += bfhi(v);
    }
    atomicAdd(&psum[g0 * FD + lane * 2], a0);
    atomicAdd(&psum[g0 * FD + lane * 2 + 1], a1);
  } else {
    int g = g0;
    for (int n = n0; n < n1; ++n) {
      int gn = batch[n];
      if (gn != g) {
        atomicAdd(&psum[g * FD + lane * 2], a0);
        atomicAdd(&psum[g * FD + lane * 2 + 1], a1);
        a0 = 0.f; a1 = 0.f; g = gn;
      }
      unsigned v = H2[(size_t)n * 64 + lane];
      a0 += bflo(v); a1 += bfhi(v);
    }
    atomicAdd(&psum[g * FD + lane * 2], a0);
    atomicAdd(&psum[g * FD + lane * 2 + 1], a1);
  }
}

__global__ void k_head(const float* __restrict__ psum, const int* __restrict__ starts,
                       const int* __restrict__ ends, const float* __restrict__ Wl,
                       const float* __restrict__ bl, float* __restrict__ out) {
  int t = threadIdx.x;  // 128 = 64 graphs x 2 classes
  int g = t >> 1, c = t & 1;
  int cnt = ends[g] - starts[g];
  if (cnt < 0) cnt = 0;
  float inv = 1.f / (float)(cnt > 0 ? cnt : 1);
  float acc = 0.f;
  for (int k = 0; k < FD; ++k) acc += psum[g * FD + k] * Wl[k * 2 + c];
  out[g * 2 + c] = acc * inv + bl[c];
}

// ---------------- host ----------------

extern "C" void kernel_launch(void* const* d_in, const int* in_sizes, int n_in,
                              void* d_out, int out_size, void* d_ws, size_t ws_size,
                              hipStream_t stream) {
  const float* x  = (const float*)d_in[0];
  const int* ei   = (const int*)d_in[1];
  const int* bat  = (const int*)d_in[2];
  const float* W1 = (const float*)d_in[3];
  const float* b1 = (const float*)d_in[4];
  const float* W2 = (const float*)d_in[5];
  const float* b2 = (const float*)d_in[6];
  const float* W3 = (const float*)d_in[7];
  const float* b3 = (const float*)d_in[8];
  const float* Wl = (const float*)d_in[9];
  const float* bl = (const float*)d_in[10];
  float* out = (float*)d_out;

  char* ws = (char*)d_ws;
  size_t off = 0;
  auto alloc = [&](size_t bytes) {
    void* p = ws + off;
    off += (bytes + 255) & ~(size_t)255;
    return p;
  };
  int* counts  = (int*)alloc(NN * 4);
  int* cursor  = (int*)alloc(NN * 4);
  int* indptr  = (int*)alloc((NN + 1) * 4);
  float* dinv  = (float*)alloc(NN * 4);
  int* bsum    = (int*)alloc(NB * 4);
  int* eb      = (int*)alloc(NB * 4);
  int* starts  = (int*)alloc(NG * 4);
  int* ends    = (int*)alloc(NG * 4);
  float* psum  = (float*)alloc(NG * FD * 4);
  uint2* edges = (uint2*)alloc((size_t)EPAD * 8);
  unsigned short* Hb   = (unsigned short*)alloc((size_t)NN * FD * 2);
  unsigned short* Abuf = (unsigned short*)alloc((size_t)NN * FD * 2);
  unsigned short* WTh  = (unsigned short*)alloc(3 * FD * FD * 2);
  unsigned short* WTl  = (unsigned short*)alloc(3 * FD * FD * 2);

  const int* row = ei;
  const int* col = ei + NE;

  // counts + cursor are adjacent in ws: single memset covers both (and the pad gap)
  hipMemsetAsync(counts, 0, (size_t)((char*)cursor - (char*)counts) + NN * 4, stream);
  hipMemsetAsync(edges, 0, (size_t)EPAD * 8, stream);
  k_prep<<<(NN + 255) / 256, 256, 0, stream>>>(W1, W2, W3, WTh, WTl, psum, bat, starts, ends);
  k_count<<<(NE + 255) / 256, 256, 0, stream>>>(col, counts);
  k_bsum<<<NB, 1024, 0, stream>>>(counts, bsum, dinv);
  k_bscan<<<1, 128, 0, stream>>>(bsum, eb);
  k_scan2<<<NB, 1024, 0, stream>>>(counts, eb, indptr);
  k_fill<<<(NE + 255) / 256, 256, 0, stream>>>(row, col, indptr, cursor, dinv, edges);

  int aggGrid = (NN + 15) / 16;       // 16 nodes per block (4 per wave x 4 waves)
  int poolGrid = ((NN + PW - 1) / PW * 64 + 255) / 256;

  k_gemm<1><<<GEMM_BLOCKS, 256, 0, stream>>>(x, WTh, WTl, Hb);
  k_agg<<<aggGrid, 256, 0, stream>>>((const uint4*)Hb, indptr, edges, dinv, b1,
                                     (uint4*)Abuf, 1);
  k_gemm<0><<<GEMM_BLOCKS, 256, 0, stream>>>(Abuf, WTh + FD * FD, WTl + FD * FD, Hb);
  k_agg<<<aggGrid, 256, 0, stream>>>((const uint4*)Hb, indptr, edges, dinv, b2,
                                     (uint4*)Abuf, 1);
  k_gemm<0><<<GEMM_BLOCKS, 256, 0, stream>>>(Abuf, WTh + 2 * FD * FD, WTl + 2 * FD * FD, Hb);
  k_agg<<<aggGrid, 256, 0, stream>>>((const uint4*)Hb, indptr, edges, dinv, b3,
                                     (uint4*)Abuf, 0);

  k_pool<<<poolGrid, 256, 0, stream>>>((const unsigned*)Abuf, bat, psum);
  k_head<<<1, 128, 0, stream>>>(psum, starts, ends, Wl, bl, out);
}